// Round 12
// baseline (1267.549 us; speedup 1.0000x reference)
//
#include <hip/hip_runtime.h>
#include <hip/hip_bf16.h>
#include <math.h>

typedef unsigned short u16;
typedef __attribute__((ext_vector_type(4))) unsigned short u16x4;
typedef __attribute__((ext_vector_type(8))) unsigned short u16x8;
typedef __attribute__((ext_vector_type(8))) short s16x8;
typedef __attribute__((ext_vector_type(4))) float f32x4;

typedef const __attribute__((address_space(1))) void* gas_t;
typedef __attribute__((address_space(3))) void* las_t;

#define DI __device__ __forceinline__

static constexpr int Bc = 64, Nc = 128, Dc = 1024, Hc = 16, HDc = 64, Ic = 4096, Lc = 4;
static constexpr int Mrows = Bc * Nc; // 8192

DI float b2f(u16 u) { union { unsigned i; float f; } x; x.i = ((unsigned)u) << 16; return x.f; }
DI u16 f2b(float f) {
  union { float f; unsigned i; } x; x.f = f;
  unsigned r = x.i + 0x7FFF + ((x.i >> 16) & 1);
  return (u16)(r >> 16);
}

#define BARRIER do { asm volatile("" ::: "memory"); __builtin_amdgcn_s_barrier(); asm volatile("" ::: "memory"); } while (0)
#define VMC(N) asm volatile("s_waitcnt vmcnt(" #N ")" ::: "memory")

// stage a (waves*16)-row half-tile: per wave 16 rows, 2 glls x 64 lanes x 16B
#define STG(PTR, ROW0, T, SLOT) do { \
    const u16* _s = (PTR) + (size_t)((ROW0) + srow) * K + (((T) << 6) + scol); \
    __builtin_amdgcn_global_load_lds((gas_t)_s, (las_t)(smem + (SLOT) + ldsw), 16, 0, 0); \
    __builtin_amdgcn_global_load_lds((gas_t)(_s + ((size_t)K << 3)), (las_t)(smem + (SLOT) + ldsw + 1024), 16, 0, 0); \
  } while (0)

// ===========================================================================
// 256x256 GEMM, BK=64, 8 waves (2M x 4N), LDS 128 KiB. 4 merged phases/iter
// (was 8): each = {reads + STG} BARRIER {32 MFMA} BARRIER. Invariants kept:
// read only after VMC-retire + barrier; re-stage only after last reads were
// MFMA(lgkm)-consumed >=1 barrier earlier. Staging: Q1:b1A0,b1A1 Q2:b0B0,b0B1
// Q3:b0A0,b0A1 Q4:b1B0,b1B1. VMC(4)@Q2 (retires b1A+older), VMC(4)@Q4
// (retires b0A/b0B+older).
// ===========================================================================
#define LDA(BUFB, RH) do { \
    _Pragma("unroll") \
    for (int mi = 0; mi < 4; ++mi) { \
      af[mi][0] = *(const s16x8*)(smem + (BUFB) + Abase_rd + (RH) * 8192 + mi * 2048 + aoff0); \
      af[mi][1] = *(const s16x8*)(smem + (BUFB) + Abase_rd + (RH) * 8192 + mi * 2048 + aoff1); \
    } } while (0)

#define LDB(DST, BUFB, CH) do { \
    _Pragma("unroll") \
    for (int nj = 0; nj < 2; ++nj) { \
      DST[nj][0] = *(const s16x8*)(smem + (BUFB) + Bbase_rd + (CH) * 4096 + nj * 2048 + aoff0); \
      DST[nj][1] = *(const s16x8*)(smem + (BUFB) + Bbase_rd + (CH) * 4096 + nj * 2048 + aoff1); \
    } } while (0)

#define MFMAQ(RH, CH, BF) do { \
    __builtin_amdgcn_s_setprio(1); \
    _Pragma("unroll") \
    for (int kk = 0; kk < 2; ++kk) \
      _Pragma("unroll") \
      for (int mi = 0; mi < 4; ++mi) \
        _Pragma("unroll") \
        for (int nj = 0; nj < 2; ++nj) \
          acc[(RH) * 4 + mi][(CH) * 2 + nj] = __builtin_amdgcn_mfma_f32_16x16x32_bf16( \
              af[mi][kk], BF[nj][kk], acc[(RH) * 4 + mi][(CH) * 2 + nj], 0, 0, 0); \
    __builtin_amdgcn_s_setprio(0); \
  } while (0)

template <int EPI, bool SPLIT>
__global__ __launch_bounds__(512, 2) void gemm256(
    const u16* __restrict__ A, const u16* __restrict__ BT,
    const float* __restrict__ bias, const float* __restrict__ bias2,
    const u16* __restrict__ resid, u16* __restrict__ C, u16* __restrict__ C2,
    int M, int N, int K, int NC) {
  extern __shared__ __align__(16) char smem[];
  const int tid = threadIdx.x;
  const int l = tid & 63;
  const int w = tid >> 6;
  const int wr = w >> 2, wc = w & 3;

  const int GX = gridDim.x;
  int wg = blockIdx.y * GX + blockIdx.x;
  const int nwg = GX * gridDim.y;
  wg = (wg & 7) * (nwg >> 3) + (wg >> 3);
  const int bn0 = (wg % GX) * 256;
  const int bm0 = (wg / GX) * 256;

  const int NT = K >> 6;
  const int NI = NT >> 1;

  const int row_l = l & 15;
  const int kl = (l >> 4) * 8;
  const int xr = (row_l & 7) << 3;
  const int aoff0 = row_l * 128 + (((0 * 32 + kl) ^ xr) * 2);
  const int aoff1 = row_l * 128 + (((1 * 32 + kl) ^ xr) * 2);
  const int Abase_rd = wr * 16384;
  const int Bbase_rd = 32768 + (wc >> 1) * 16384 + (wc & 1) * 8192;

  const int srow = w * 16 + (l >> 3);
  const int scol = ((l & 7) ^ ((l >> 3) & 7)) << 3;
  const int ldsw = w * 2048;

  enum { b0A0 = 0, b0A1 = 16384, b0B0 = 32768, b0B1 = 49152,
         b1A0 = 65536, b1A1 = 81920, b1B0 = 98304, b1B1 = 114688 };

  STG(BT, bn0, 0, b0B0);
  STG(BT, bn0 + 128, 0, b0B1);
  STG(A, bm0, 0, b0A0);
  STG(A, bm0 + 128, 0, b0A1);
  STG(BT, bn0, 1, b1B0);
  STG(BT, bn0 + 128, 1, b1B1);
  VMC(4);
  BARRIER;

  f32x4 acc[8][4];
#pragma unroll
  for (int i = 0; i < 8; ++i)
#pragma unroll
    for (int j = 0; j < 4; ++j) acc[i][j] = f32x4{0.f, 0.f, 0.f, 0.f};
  s16x8 af[4][2], bf0[2][2], bf1[2][2];

  for (int j = 0; j < NI; ++j) {
    const int t1 = 2 * j + 1;
    int t2 = 2 * j + 2; if (t2 >= NT) t2 = 0;
    int t3 = 2 * j + 3; if (t3 >= NT) t3 = 1;
    // Q1: reads b0 {A R0, B C0, B C1}; stage b1A0,b1A1; MFMA (0,0)+(0,1)
    LDA(0, 0); LDB(bf0, 0, 0); LDB(bf1, 0, 1);
    STG(A, bm0, t1, b1A0);
    STG(A, bm0 + 128, t1, b1A1);
    BARRIER; MFMAQ(0, 0, bf0); MFMAQ(0, 1, bf1); BARRIER;
    // Q2: reads b0 {A R1}; stage b0B0,b0B1 [b0B last read Q1, consumed];
    //     VMC(4) retires b1A (Q1) + prev b1B -> Q3's b1 reads safe
    LDA(0, 1);
    STG(BT, bn0, t2, b0B0);
    STG(BT, bn0 + 128, t2, b0B1);
    VMC(4);
    BARRIER; MFMAQ(1, 0, bf0); MFMAQ(1, 1, bf1); BARRIER;
    // Q3: reads b1 {A R0, B C0, C1}; stage b0A0,b0A1 [b0A last read Q2, consumed]
    LDA(65536, 0); LDB(bf0, 65536, 0); LDB(bf1, 65536, 1);
    STG(A, bm0, t2, b0A0);
    STG(A, bm0 + 128, t2, b0A1);
    BARRIER; MFMAQ(0, 0, bf0); MFMAQ(0, 1, bf1); BARRIER;
    // Q4: reads b1 {A R1}; stage b1B0,b1B1 [b1B last read Q3, consumed];
    //     VMC(4) retires b0B (Q2) + b0A (Q3) -> next Q1's b0 reads safe
    LDA(65536, 1);
    STG(BT, bn0, t3, b1B0);
    STG(BT, bn0 + 128, t3, b1B1);
    VMC(4);
    BARRIER; MFMAQ(1, 0, bf0); MFMAQ(1, 1, bf1); BARRIER;
  }

  u16* Cout = C;
  const float* bi = bias;
  int cb = bn0;
  if (SPLIT) {
    const int half = N >> 1;
    if (bn0 >= half) { Cout = C2; bi = bias2; cb = bn0 - half; }
  }
  const int r0 = bm0 + wr * 128 + ((l >> 4) << 2);
#pragma unroll
  for (int fi = 0; fi < 8; ++fi) {
#pragma unroll
    for (int fj = 0; fj < 4; ++fj) {
      const int ocol = cb + wc * 64 + fj * 16 + (l & 15);
      const float bv = bi[ocol];
      const int row = r0 + fi * 16;
#pragma unroll
      for (int r = 0; r < 4; ++r) {
        float v = acc[fi][fj][r] + bv;
        if constexpr (EPI == 1) v += b2f(resid[(size_t)(row + r) * NC + ocol]);
        if constexpr (EPI == 2) v = 0.5f * v * (1.f + erff(v * 0.70710678118654752f));
        if constexpr (EPI == 3) v = tanhf(v);
        Cout[(size_t)(row + r) * NC + ocol] = f2b(v);
      }
    }
  }
}

// ===========================================================================
// 256x128 GEMM, BK=64, 8 waves (4M x 2N), LDS 96 KiB. 4 merged phases/iter.
// Staging: Q1:c1A0,c1A1 Q2:c0B Q3:c0A0,c0A1 Q4:c1B. VMC(2)@Q2, VMC(2)@Q4.
// ===========================================================================
#define LDA2(BUFB, RH) do { \
    _Pragma("unroll") \
    for (int mi = 0; mi < 2; ++mi) { \
      af[mi][0] = *(const s16x8*)(smem + (BUFB) + Abase_rd + ((RH) * 2 + mi) * 2048 + aoff0); \
      af[mi][1] = *(const s16x8*)(smem + (BUFB) + Abase_rd + ((RH) * 2 + mi) * 2048 + aoff1); \
    } } while (0)

#define MFMAQ2(RH, CH, BF) do { \
    __builtin_amdgcn_s_setprio(1); \
    _Pragma("unroll") \
    for (int kk = 0; kk < 2; ++kk) \
      _Pragma("unroll") \
      for (int mi = 0; mi < 2; ++mi) \
        _Pragma("unroll") \
        for (int nj = 0; nj < 2; ++nj) \
          acc[(RH) * 2 + mi][(CH) * 2 + nj] = __builtin_amdgcn_mfma_f32_16x16x32_bf16( \
              af[mi][kk], BF[nj][kk], acc[(RH) * 2 + mi][(CH) * 2 + nj], 0, 0, 0); \
    __builtin_amdgcn_s_setprio(0); \
  } while (0)

template <int EPI>
__global__ __launch_bounds__(512, 2) void gemm128n(
    const u16* __restrict__ A, const u16* __restrict__ BT,
    const float* __restrict__ bias, const u16* __restrict__ resid,
    u16* __restrict__ C, int M, int N, int K, int NC) {
  extern __shared__ __align__(16) char smem[];
  const int tid = threadIdx.x;
  const int l = tid & 63;
  const int w = tid >> 6;
  const int wr = w >> 1, wc = w & 1;

  const int GX = gridDim.x;
  int wg = blockIdx.y * GX + blockIdx.x;
  const int nwg = GX * gridDim.y;
  wg = (wg & 7) * (nwg >> 3) + (wg >> 3);
  const int bn0 = (wg % GX) * 128;
  const int bm0 = (wg / GX) * 256;

  const int NT = K >> 6;
  const int NI = NT >> 1;

  const int row_l = l & 15;
  const int kl = (l >> 4) * 8;
  const int xr = (row_l & 7) << 3;
  const int aoff0 = row_l * 128 + (((0 * 32 + kl) ^ xr) * 2);
  const int aoff1 = row_l * 128 + (((1 * 32 + kl) ^ xr) * 2);
  const int Abase_rd = (wr >> 1) * 16384 + (wr & 1) * 8192;
  const int Bbase_rd = 32768 + wc * 8192;

  const int srow = w * 16 + (l >> 3);
  const int scol = ((l & 7) ^ ((l >> 3) & 7)) << 3;
  const int ldsw = w * 2048;

  enum { c0A0 = 0, c0A1 = 16384, c0B = 32768,
         c1A0 = 49152, c1A1 = 65536, c1B = 81920 };

  STG(BT, bn0, 0, c0B);
  STG(A, bm0, 0, c0A0);
  STG(A, bm0 + 128, 0, c0A1);
  STG(BT, bn0, 1, c1B);
  VMC(2);
  BARRIER;

  f32x4 acc[4][4];
#pragma unroll
  for (int i = 0; i < 4; ++i)
#pragma unroll
    for (int j = 0; j < 4; ++j) acc[i][j] = f32x4{0.f, 0.f, 0.f, 0.f};
  s16x8 af[2][2], bf0[2][2], bf1[2][2];

  for (int j = 0; j < NI; ++j) {
    const int t1 = 2 * j + 1;
    int t2 = 2 * j + 2; if (t2 >= NT) t2 = 0;
    int t3 = 2 * j + 3; if (t3 >= NT) t3 = 1;
    // Q1: reads c0 {A RH0, B C0, C1}; stage c1A0,c1A1
    LDA2(0, 0); LDB(bf0, 0, 0); LDB(bf1, 0, 1);
    STG(A, bm0, t1, c1A0);
    STG(A, bm0 + 128, t1, c1A1);
    BARRIER; MFMAQ2(0, 0, bf0); MFMAQ2(0, 1, bf1); BARRIER;
    // Q2: reads c0 {A RH1}; stage c0B [last read Q1, consumed];
    //     VMC(2) retires c1A (Q1) + prev c1B -> Q3's c1 reads safe
    LDA2(0, 1);
    STG(BT, bn0, t2, c0B);
    VMC(2);
    BARRIER; MFMAQ2(1, 0, bf0); MFMAQ2(1, 1, bf1); BARRIER;
    // Q3: reads c1 {A RH0, B C0, C1}; stage c0A0,c0A1 [last read Q2, consumed]
    LDA2(49152, 0); LDB(bf0, 49152, 0); LDB(bf1, 49152, 1);
    STG(A, bm0, t2, c0A0);
    STG(A, bm0 + 128, t2, c0A1);
    BARRIER; MFMAQ2(0, 0, bf0); MFMAQ2(0, 1, bf1); BARRIER;
    // Q4: reads c1 {A RH1}; stage c1B [last read Q3, consumed];
    //     VMC(2) retires c0B (Q2) + c0A (Q3) -> next Q1's c0 reads safe
    LDA2(49152, 1);
    STG(BT, bn0, t3, c1B);
    VMC(2);
    BARRIER; MFMAQ2(1, 0, bf0); MFMAQ2(1, 1, bf1); BARRIER;
  }

  const int r0 = bm0 + wr * 64 + ((l >> 4) << 2);
#pragma unroll
  for (int fi = 0; fi < 4; ++fi) {
#pragma unroll
    for (int fj = 0; fj < 4; ++fj) {
      const int ocol = bn0 + wc * 64 + fj * 16 + (l & 15);
      const float bv = bias[ocol];
      const int row = r0 + fi * 16;
#pragma unroll
      for (int r = 0; r < 4; ++r) {
        float v = acc[fi][fj][r] + bv;
        if constexpr (EPI == 1) v += b2f(resid[(size_t)(row + r) * NC + ocol]);
        if constexpr (EPI == 2) v = 0.5f * v * (1.f + erff(v * 0.70710678118654752f));
        if constexpr (EPI == 3) v = tanhf(v);
        C[(size_t)(row + r) * NC + ocol] = f2b(v);
      }
    }
  }
}

// ---------------------------------------------------------------------------
// transpose helpers (f32 -> bf16)
// ---------------------------------------------------------------------------
DI void ttile(const float* in, u16* out, int R, int C, int r0, int c0, int t) {
  __shared__ u16 tile[32][33];
  const int lr = t >> 3;
  const int lc = (t & 7) * 4;
  f32x4 v = *(const f32x4*)(in + (size_t)(r0 + lr) * C + c0 + lc);
#pragma unroll
  for (int j = 0; j < 4; ++j) tile[lr][lc + j] = f2b(v[j]);
  __syncthreads();
  u16x4 o;
#pragma unroll
  for (int j = 0; j < 4; ++j) o[j] = tile[lc + j][lr];
  *(u16x4*)(out + (size_t)(c0 + lr) * R + r0 + lc) = o;
}

__global__ __launch_bounds__(256) void transpose_cvt(
    const float* __restrict__ in, u16* __restrict__ out, int R, int C) {
  ttile(in, out, R, C, blockIdx.y * 32, blockIdx.x * 32, threadIdx.x);
}

__global__ __launch_bounds__(256) void transpose4sq(
    const float* s0, const float* s1, const float* s2, const float* s3,
    u16* d0, u16* d1, u16* d2, u16* d3) {
  const int z = blockIdx.z;
  const float* in = z == 0 ? s0 : z == 1 ? s1 : z == 2 ? s2 : s3;
  u16* out = z == 0 ? d0 : z == 1 ? d1 : z == 2 ? d2 : d3;
  ttile(in, out, 1024, 1024, blockIdx.y * 32, blockIdx.x * 32, threadIdx.x);
}

__global__ __launch_bounds__(256) void transpose_io(
    const float* si, u16* di, const float* so, u16* dout) {
  if (blockIdx.z == 0) {
    ttile(si, di, 1024, 4096, blockIdx.y * 32, blockIdx.x * 32, threadIdx.x);
  } else {
    ttile(so, dout, 4096, 1024, blockIdx.x * 32, blockIdx.y * 32, threadIdx.x);
  }
}

__global__ __launch_bounds__(256) void cvt_k(
    const float* __restrict__ in, u16* __restrict__ out) {
  const size_t i = ((size_t)blockIdx.x * 256 + threadIdx.x) * 8;
  f32x4 a = *(const f32x4*)(in + i);
  f32x4 b = *(const f32x4*)(in + i + 4);
  u16x8 o;
#pragma unroll
  for (int j = 0; j < 4; ++j) o[j] = f2b(a[j]);
#pragma unroll
  for (int j = 0; j < 4; ++j) o[4 + j] = f2b(b[j]);
  *(u16x8*)(out + i) = o;
}

// ---------------------------------------------------------------------------
// Fused additive attention (r11, proven): gq -> gk -> u = q*gk per (b,h).
// ---------------------------------------------------------------------------
__global__ __launch_bounds__(128) void attn_fused(
    const u16* __restrict__ q, const u16* __restrict__ k,
    const float* __restrict__ hwq, const float* __restrict__ hwk,
    u16* __restrict__ u) {
  const int bh = blockIdx.x;
  const int b = bh >> 4, h = bh & 15;
  const int tid = threadIdx.x;
  const int lane = tid & 63, wv = tid >> 6;
  const int d = tid & 63, half = tid >> 6;
  __shared__ float hw[64];
  __shared__ float gqs[64];
  __shared__ float gks[64];
  __shared__ float ex[128];
  __shared__ float part[64];
  __shared__ float xw[4];

  // ---- phase 1: gq ----
  if (tid < 64) hw[tid] = hwq[h * 64 + tid];
  __syncthreads();
  const u16* qrow = q + ((size_t)(b * 128 + tid)) * Dc + h * 64;
  float s = 0.f;
#pragma unroll
  for (int c = 0; c < 8; ++c) {
    u16x8 v = *(const u16x8*)(qrow + c * 8);
#pragma unroll
    for (int j = 0; j < 8; ++j) s += b2f(v[j]) * hw[c * 8 + j];
  }
  s *= 0.125f;
  float m = s;
  for (int o = 32; o; o >>= 1) m = fmaxf(m, __shfl_xor(m, o));
  if (lane == 0) xw[wv] = m;
  __syncthreads();
  m = fmaxf(xw[0], xw[1]);
  float e = __expf(s - m);
  ex[tid] = e;
  float sm = e;
  for (int o = 32; o; o >>= 1) sm += __shfl_xor(sm, o);
  if (lane == 0) xw[2 + wv] = sm;
  __syncthreads();
  float sum = xw[2] + xw[3];
  {
    const u16* colp = q + ((size_t)(b * 128 + half * 64)) * Dc + h * 64 + d;
    float acc = 0.f;
    for (int t = 0; t < 64; ++t) acc += ex[half * 64 + t] * b2f(colp[(size_t)t * Dc]);
    if (half == 0) part[d] = acc;
    __syncthreads();
    if (half == 1) gqs[d] = (part[d] + acc) / sum;
  }
  __syncthreads();

  // ---- phase 2: gk ----
  if (tid < 64) hw[tid] = hwk[h * 64 + tid];
  __syncthreads();
  const u16* krow = k + ((size_t)(b * 128 + tid)) * Dc + h * 64;
  s = 0.f;
#pragma unroll
  for (int c = 0; c < 8; ++c) {
    u16x8 v = *(const u16x8*)(krow + c * 8);
#pragma unroll
    for (int j = 0; j < 8; ++j) s += b2f(v[j]) * gqs[c * 8 + j] * hw[c * 8 + j];
  }
  s *= 0.125f;
  m = s;
  for (int o = 32; o; o >>= 1) m = fmaxf(m, __shfl_xor(m, o));
  if (lane == 0) xw[wv] = m;
  __syncthreads();
  m = fmaxf(xw[0], xw[1]);
  e = __expf(s - m);
  ex[tid] = e;
  sm = e;
  for (int o = 32; o; o >>= 1) sm += __shfl_xor(sm, o);
  if (lane == 0) xw[2 + wv] = sm;
  __syncthreads();
  sum = xw[2] + xw[3];
  {
    const u16* colp = k + ((size_t)(b * 128 + half * 64)) * Dc + h * 64 + d;
    float acc = 0.f;
    for (int t = 0; t < 64; ++t) acc += ex[half * 64 + t] * b2f(colp[(size_t)t * Dc]);
    acc *= gqs[d];
    if (half == 0) part[d] = acc;
    __syncthreads();
    if (half == 1) gks[d] = (part[d] + acc) / sum;
  }
  __syncthreads();

  // ---- phase 3: u = q * gk ----
  const float g = gks[d];
  const u16* qp = q + (size_t)b * 128 * Dc + h * 64 + d;
  u16* up = u + (size_t)b * 128 * Dc + h * 64 + d;
  for (int t = half; t < 128; t += 2) {
    up[(size_t)t * Dc] = f2b(b2f(qp[(size_t)t * Dc]) * g);
  }
}

__global__ __launch_bounds__(256) void ln_k(
    const u16* __restrict__ in, const float* __restrict__ g,
    const float* __restrict__ bta, u16* __restrict__ out) {
  const int row = blockIdx.x, tid = threadIdx.x;
  const int lane = tid & 63, wave = tid >> 6;
  __shared__ float red[8];
  const u16* p = in + (size_t)row * Dc + tid * 4;
  u16x4 v = *(const u16x4*)p;
  float x[4];
  float s = 0.f, sq = 0.f;
#pragma unroll
  for (int j = 0; j < 4; ++j) {
    x[j] = b2f(v[j]);
    s += x[j];
    sq += x[j] * x[j];
  }
  for (int o = 32; o; o >>= 1) {
    s += __shfl_down(s, o);
    sq += __shfl_down(sq, o);
  }
  if (lane == 0) {
    red[wave] = s;
    red[4 + wave] = sq;
  }
  __syncthreads();
  s = red[0] + red[1] + red[2] + red[3];
  sq = red[4] + red[5] + red[6] + red[7];
  const float mean = s * (1.f / 1024.f);
  const float var = sq * (1.f / 1024.f) - mean * mean;
  const float rs = rsqrtf(var + 1e-12f);
  f32x4 gv = *(const f32x4*)(g + tid * 4);
  f32x4 bv = *(const f32x4*)(bta + tid * 4);
  u16x4 o;
#pragma unroll
  for (int j = 0; j < 4; ++j) o[j] = f2b((x[j] - mean) * rs * gv[j] + bv[j]);
  *(u16x4*)(out + (size_t)row * Dc + tid * 4) = o;
}

__global__ __launch_bounds__(256) void pool_k(
    const u16* __restrict__ s1, const float* __restrict__ pq,
    const u16* __restrict__ h, float* __restrict__ out) {
  const int b = blockIdx.x, tid = threadIdx.x;
  __shared__ float pqs[1024];
  __shared__ float sc[128];
  __shared__ float ex[128];
  for (int i = tid; i < 1024; i += 256) pqs[i] = pq[i];
  __syncthreads();
  if (tid < 128) {
    const u16* row = s1 + ((size_t)(b * 128 + tid)) * Dc;
    float s = 0.f;
    for (int c = 0; c < 128; ++c) {
      u16x8 v = *(const u16x8*)(row + c * 8);
#pragma unroll
      for (int j = 0; j < 8; ++j) s += b2f(v[j]) * pqs[c * 8 + j];
    }
    sc[tid] = s;
  }
  __syncthreads();
  float m = -1e30f;
  for (int t = 0; t < 128; ++t) m = fmaxf(m, sc[t]);
  if (tid < 128) ex[tid] = __expf(sc[tid] - m);
  __syncthreads();
  float sum = 0.f;
  for (int t = 0; t < 128; ++t) sum += ex[t];
  const int d0 = tid * 4;
  float acc[4] = {0.f, 0.f, 0.f, 0.f};
  for (int n = 0; n < 128; ++n) {
    const float w = ex[n];
    u16x4 v = *(const u16x4*)(h + ((size_t)(b * 128 + n)) * Dc + d0);
#pragma unroll
    for (int j = 0; j < 4; ++j) acc[j] += w * b2f(v[j]);
  }
  const float inv = 1.f / sum;
  f32x4 o;
#pragma unroll
  for (int j = 0; j < 4; ++j) o[j] = acc[j] * inv;
  *(f32x4*)(out + b * Dc + d0) = o;
}

// ---------------------------------------------------------------------------
extern "C" void kernel_launch(void* const* d_in, const int* in_sizes, int n_in,
                              void* d_out, int out_size, void* d_ws, size_t ws_size,
                              hipStream_t stream) {
  const float* x = (const float*)d_in[0];
  const float* wq_w = (const float*)d_in[1];
  const float* wq_b = (const float*)d_in[2];
  const float* wk_w = (const float*)d_in[3];
  const float* wk_b = (const float*)d_in[4];
  const float* hwq = (const float*)d_in[5];
  const float* hwk = (const float*)d_in[6];
  const float* tr_w = (const float*)d_in[7];
  const float* tr_b = (const float*)d_in[8];
  const float* so_w = (const float*)d_in[9];
  const float* so_b = (const float*)d_in[10];
  const float* ln1g = (const float*)d_in[11];
  const float* ln1b = (const float*)d_in[12];
  const float* int_w = (const float*)d_in[13];
  const float* int_b = (const float*)d_in[14];
  const float* out_w = (const float*)d_in[15];
  const float* out_b = (const float*)d_in[16];
  const float* ln2g = (const float*)d_in[17];
  const float* ln2b = (const float*)d_in[18];
  const float* pool_w = (const float*)d_in[19];
  const float* pool_b = (const float*)d_in[20];
  const float* pool_q = (const float*)d_in[21];

  char* w = (char*)d_ws;
  auto alloc = [&](size_t bytes) {
    char* p = w;
    w += (bytes + 255) & ~(size_t)255;
    return p;
  };
  u16* wTqk = (u16*)alloc((size_t)2 * Dc * Dc * 2);
  u16* wTtr = (u16*)alloc((size_t)Dc * Dc * 2);
  u16* wTso = (u16*)alloc((size_t)Dc * Dc * 2);
  u16* wTint = (u16*)alloc((size_t)Dc * Ic * 2);
  u16* wTout = (u16*)alloc((size_t)Dc * Ic * 2);
  u16* wTpool = (u16*)alloc((size_t)Dc * Dc * 2);
  u16* qb = (u16*)alloc((size_t)Mrows * Dc * 2);
  u16* kb = (u16*)alloc((size_t)Mrows * Dc * 2);
  u16* ab = (u16*)alloc((size_t)Mrows * Dc * 2);
  u16* tb = (u16*)alloc((size_t)Mrows * Dc * 2);
  u16* xc = (u16*)alloc((size_t)Mrows * Dc * 2);
  u16* hb = (u16*)alloc((size_t)Mrows * Ic * 2);
  if ((size_t)(w - (char*)d_ws) > ws_size) return;

  static constexpr size_t LDSB = 131072;
  static constexpr size_t LDSB2 = 98304;
  hipFuncSetAttribute((const void*)gemm256<0, true>, hipFuncAttributeMaxDynamicSharedMemorySize, LDSB);
  hipFuncSetAttribute((const void*)gemm256<2, false>, hipFuncAttributeMaxDynamicSharedMemorySize, LDSB);
  hipFuncSetAttribute((const void*)gemm128n<0>, hipFuncAttributeMaxDynamicSharedMemorySize, LDSB2);
  hipFuncSetAttribute((const void*)gemm128n<1>, hipFuncAttributeMaxDynamicSharedMemorySize, LDSB2);
  hipFuncSetAttribute((const void*)gemm128n<3>, hipFuncAttributeMaxDynamicSharedMemorySize, LDSB2);

  const dim3 blk(256);
  const dim3 blkG(512);
  const dim3 gT1(Dc / 32, Dc / 32);
  const dim3 gT4(Dc / 32, Dc / 32, 4);
  const dim3 gTio(Ic / 32, Dc / 32, 2);
  const dim3 gQK(2048 / 256, Mrows / 256);  // (8,32) = 256 blocks
  const dim3 gNi(Ic / 256, Mrows / 256);    // (16,32) = 512 blocks
  const dim3 gO(Dc / 128, Mrows / 256);     // (8,32) = 256 blocks

  cvt_k<<<(Mrows * Dc) / (256 * 8), blk, 0, stream>>>(x, xc);

  for (int i = 0; i < Lc; ++i) {
    transpose4sq<<<gT4, blk, 0, stream>>>(
        wq_w + (size_t)i * Dc * Dc, wk_w + (size_t)i * Dc * Dc,
        tr_w + (size_t)i * Dc * Dc, so_w + (size_t)i * Dc * Dc,
        wTqk, wTqk + (size_t)Dc * Dc, wTtr, wTso);
    transpose_io<<<gTio, blk, 0, stream>>>(
        int_w + (size_t)i * Dc * Ic, wTint, out_w + (size_t)i * Ic * Dc, wTout);

    // q | k = x @ [Wq ; Wk] (fused N=2048, split outputs)
    gemm256<0, true><<<gQK, blkG, LDSB, stream>>>(xc, wTqk, wq_b + i * Dc, wk_b + i * Dc,
                                                  nullptr, qb, kb, Mrows, 2048, Dc, Dc);
    // gq -> gk -> u = q*gk, one dispatch; u written into kb (head-local cols)
    attn_fused<<<Bc * Hc, 128, 0, stream>>>(qb, kb, hwq + i * Hc * HDc,
                                            hwk + i * Hc * HDc, kb);
    // attn_out = u@tr + tr_b + q
    gemm128n<1><<<gO, blkG, LDSB2, stream>>>(kb, wTtr, tr_b + i * Dc, qb, tb, Mrows, Dc, Dc, Dc);
    // t2 = attn_out@so + so_b ; a = LN1(t2)
    gemm128n<0><<<gO, blkG, LDSB2, stream>>>(tb, wTso, so_b + i * Dc, nullptr, kb, Mrows, Dc, Dc, Dc);
    ln_k<<<Mrows, blk, 0, stream>>>(kb, ln1g + i * Dc, ln1b + i * Dc, ab);
    // h = gelu(a@int + int_b)
    gemm256<2, false><<<gNi, blkG, LDSB, stream>>>(ab, wTint, int_b + i * Ic, nullptr,
                                                   nullptr, hb, nullptr, Mrows, Ic, Dc, Ic);
    // o+a = h@out + out_b + a ; x = LN2
    gemm128n<1><<<gO, blkG, LDSB2, stream>>>(hb, wTout, out_b + i * Dc, ab, tb, Mrows, Dc, Ic, Dc);
    ln_k<<<Mrows, blk, 0, stream>>>(tb, ln2g + i * Dc, ln2b + i * Dc, xc);
  }

  transpose_cvt<<<gT1, blk, 0, stream>>>(pool_w, wTpool, Dc, Dc);
  gemm128n<3><<<gO, blkG, LDSB2, stream>>>(xc, wTpool, pool_b, nullptr, tb, Mrows, Dc, Dc, Dc);
  pool_k<<<Bc, blk, 0, stream>>>(tb, pool_q, xc, (float*)d_out);
}

// Round 13
// 1222.376 us; speedup vs baseline: 1.0370x; 1.0370x over previous
//
#include <hip/hip_runtime.h>
#include <hip/hip_bf16.h>
#include <math.h>

typedef unsigned short u16;
typedef __attribute__((ext_vector_type(4))) unsigned short u16x4;
typedef __attribute__((ext_vector_type(8))) unsigned short u16x8;
typedef __attribute__((ext_vector_type(8))) short s16x8;
typedef __attribute__((ext_vector_type(4))) float f32x4;

typedef const __attribute__((address_space(1))) void* gas_t;
typedef __attribute__((address_space(3))) void* las_t;

#define DI __device__ __forceinline__

static constexpr int Bc = 64, Nc = 128, Dc = 1024, Hc = 16, HDc = 64, Ic = 4096, Lc = 4;
static constexpr int Mrows = Bc * Nc; // 8192

DI float b2f(u16 u) { union { unsigned i; float f; } x; x.i = ((unsigned)u) << 16; return x.f; }
DI u16 f2b(float f) {
  union { float f; unsigned i; } x; x.f = f;
  unsigned r = x.i + 0x7FFF + ((x.i >> 16) & 1);
  return (u16)(r >> 16);
}

#define BARRIER do { asm volatile("" ::: "memory"); __builtin_amdgcn_s_barrier(); asm volatile("" ::: "memory"); } while (0)
#define VMC(N) asm volatile("s_waitcnt vmcnt(" #N ")" ::: "memory")

// stage a (waves*16)-row half-tile: per wave 16 rows, 2 glls x 64 lanes x 16B
#define STG(PTR, ROW0, T, SLOT) do { \
    const u16* _s = (PTR) + (size_t)((ROW0) + srow) * K + (((T) << 6) + scol); \
    __builtin_amdgcn_global_load_lds((gas_t)_s, (las_t)(smem + (SLOT) + ldsw), 16, 0, 0); \
    __builtin_amdgcn_global_load_lds((gas_t)(_s + ((size_t)K << 3)), (las_t)(smem + (SLOT) + ldsw + 1024), 16, 0, 0); \
  } while (0)

// ===========================================================================
// 256x256 8-phase GEMM, BK=64, 8 waves (2M x 4N). LDS 128 KiB. (r11 best)
// ===========================================================================
#define LDA(BUFB, RH) do { \
    _Pragma("unroll") \
    for (int mi = 0; mi < 4; ++mi) { \
      af[mi][0] = *(const s16x8*)(smem + (BUFB) + Abase_rd + (RH) * 8192 + mi * 2048 + aoff0); \
      af[mi][1] = *(const s16x8*)(smem + (BUFB) + Abase_rd + (RH) * 8192 + mi * 2048 + aoff1); \
    } } while (0)

#define LDB(DST, BUFB, CH) do { \
    _Pragma("unroll") \
    for (int nj = 0; nj < 2; ++nj) { \
      DST[nj][0] = *(const s16x8*)(smem + (BUFB) + Bbase_rd + (CH) * 4096 + nj * 2048 + aoff0); \
      DST[nj][1] = *(const s16x8*)(smem + (BUFB) + Bbase_rd + (CH) * 4096 + nj * 2048 + aoff1); \
    } } while (0)

#define MFMAQ(RH, CH, BF) do { \
    __builtin_amdgcn_s_setprio(1); \
    _Pragma("unroll") \
    for (int kk = 0; kk < 2; ++kk) \
      _Pragma("unroll") \
      for (int mi = 0; mi < 4; ++mi) \
        _Pragma("unroll") \
        for (int nj = 0; nj < 2; ++nj) \
          acc[(RH) * 4 + mi][(CH) * 2 + nj] = __builtin_amdgcn_mfma_f32_16x16x32_bf16( \
              af[mi][kk], BF[nj][kk], acc[(RH) * 4 + mi][(CH) * 2 + nj], 0, 0, 0); \
    __builtin_amdgcn_s_setprio(0); \
  } while (0)

template <int EPI, bool SPLIT>
__global__ __launch_bounds__(512, 2) void gemm256(
    const u16* __restrict__ A, const u16* __restrict__ BT,
    const float* __restrict__ bias, const float* __restrict__ bias2,
    const u16* __restrict__ resid, u16* __restrict__ C, u16* __restrict__ C2,
    int M, int N, int K, int NC) {
  extern __shared__ __align__(16) char smem[];
  const int tid = threadIdx.x;
  const int l = tid & 63;
  const int w = tid >> 6;
  const int wr = w >> 2, wc = w & 3;

  const int GX = gridDim.x;
  int wg = blockIdx.y * GX + blockIdx.x;
  const int nwg = GX * gridDim.y;
  wg = (wg & 7) * (nwg >> 3) + (wg >> 3);
  const int bn0 = (wg % GX) * 256;
  const int bm0 = (wg / GX) * 256;

  const int NT = K >> 6;
  const int NI = NT >> 1;

  const int row_l = l & 15;
  const int kl = (l >> 4) * 8;
  const int xr = (row_l & 7) << 3;
  const int aoff0 = row_l * 128 + (((0 * 32 + kl) ^ xr) * 2);
  const int aoff1 = row_l * 128 + (((1 * 32 + kl) ^ xr) * 2);
  const int Abase_rd = wr * 16384;
  const int Bbase_rd = 32768 + (wc >> 1) * 16384 + (wc & 1) * 8192;

  const int srow = w * 16 + (l >> 3);
  const int scol = ((l & 7) ^ ((l >> 3) & 7)) << 3;
  const int ldsw = w * 2048;

  enum { b0A0 = 0, b0A1 = 16384, b0B0 = 32768, b0B1 = 49152,
         b1A0 = 65536, b1A1 = 81920, b1B0 = 98304, b1B1 = 114688 };

  STG(BT, bn0, 0, b0B0);
  STG(BT, bn0 + 128, 0, b0B1);
  STG(A, bm0, 0, b0A0);
  STG(A, bm0 + 128, 0, b0A1);
  STG(BT, bn0, 1, b1B0);
  STG(BT, bn0 + 128, 1, b1B1);
  VMC(4);
  BARRIER;

  f32x4 acc[8][4];
#pragma unroll
  for (int i = 0; i < 8; ++i)
#pragma unroll
    for (int j = 0; j < 4; ++j) acc[i][j] = f32x4{0.f, 0.f, 0.f, 0.f};
  s16x8 af[4][2], bf0[2][2], bf1[2][2];

  for (int j = 0; j < NI; ++j) {
    const int t1 = 2 * j + 1;
    int t2 = 2 * j + 2; if (t2 >= NT) t2 = 0;
    int t3 = 2 * j + 3; if (t3 >= NT) t3 = 1;
    // P1
    LDA(0, 0); LDB(bf0, 0, 0);
    STG(A, bm0, t1, b1A0);
    BARRIER; MFMAQ(0, 0, bf0); BARRIER;
    // P2
    LDB(bf1, 0, 1);
    STG(A, bm0 + 128, t1, b1A1);
    BARRIER; MFMAQ(0, 1, bf1); BARRIER;
    // P3
    LDA(0, 1);
    STG(BT, bn0, t2, b0B0);
    BARRIER; MFMAQ(1, 0, bf0); BARRIER;
    // P4
    STG(BT, bn0 + 128, t2, b0B1);
    STG(A, bm0, t2, b0A0);
    VMC(6);
    BARRIER; MFMAQ(1, 1, bf1); BARRIER;
    // P5
    LDA(65536, 0); LDB(bf0, 65536, 0);
    STG(A, bm0 + 128, t2, b0A1);
    BARRIER; MFMAQ(0, 0, bf0); BARRIER;
    // P6
    LDB(bf1, 65536, 1);
    BARRIER; MFMAQ(0, 1, bf1); BARRIER;
    // P7
    LDA(65536, 1);
    STG(BT, bn0, t3, b1B0);
    BARRIER; MFMAQ(1, 0, bf0); BARRIER;
    // P8
    STG(BT, bn0 + 128, t3, b1B1);
    VMC(4);
    BARRIER; MFMAQ(1, 1, bf1); BARRIER;
  }

  u16* Cout = C;
  const float* bi = bias;
  int cb = bn0;
  if (SPLIT) {
    const int half = N >> 1;
    if (bn0 >= half) { Cout = C2; bi = bias2; cb = bn0 - half; }
  }
  const int r0 = bm0 + wr * 128 + ((l >> 4) << 2);
#pragma unroll
  for (int fi = 0; fi < 8; ++fi) {
#pragma unroll
    for (int fj = 0; fj < 4; ++fj) {
      const int ocol = cb + wc * 64 + fj * 16 + (l & 15);
      const float bv = bi[ocol];
      const int row = r0 + fi * 16;
#pragma unroll
      for (int r = 0; r < 4; ++r) {
        float v = acc[fi][fj][r] + bv;
        if constexpr (EPI == 1) v += b2f(resid[(size_t)(row + r) * NC + ocol]);
        if constexpr (EPI == 2) v = 0.5f * v * (1.f + erff(v * 0.70710678118654752f));
        if constexpr (EPI == 3) v = tanhf(v);
        Cout[(size_t)(row + r) * NC + ocol] = f2b(v);
      }
    }
  }
}

// ===========================================================================
// 256x128 8-phase GEMM, BK=64, 8 waves (4M x 2N), LDS 96 KiB. (r11 best)
// ===========================================================================
#define LDA2(BUFB, RH) do { \
    _Pragma("unroll") \
    for (int mi = 0; mi < 2; ++mi) { \
      af[mi][0] = *(const s16x8*)(smem + (BUFB) + Abase_rd + ((RH) * 2 + mi) * 2048 + aoff0); \
      af[mi][1] = *(const s16x8*)(smem + (BUFB) + Abase_rd + ((RH) * 2 + mi) * 2048 + aoff1); \
    } } while (0)

#define MFMAQ2(RH, CH, BF) do { \
    __builtin_amdgcn_s_setprio(1); \
    _Pragma("unroll") \
    for (int kk = 0; kk < 2; ++kk) \
      _Pragma("unroll") \
      for (int mi = 0; mi < 2; ++mi) \
        _Pragma("unroll") \
        for (int nj = 0; nj < 2; ++nj) \
          acc[(RH) * 2 + mi][(CH) * 2 + nj] = __builtin_amdgcn_mfma_f32_16x16x32_bf16( \
              af[mi][kk], BF[nj][kk], acc[(RH) * 2 + mi][(CH) * 2 + nj], 0, 0, 0); \
    __builtin_amdgcn_s_setprio(0); \
  } while (0)

template <int EPI>
__global__ __launch_bounds__(512, 2) void gemm128n(
    const u16* __restrict__ A, const u16* __restrict__ BT,
    const float* __restrict__ bias, const u16* __restrict__ resid,
    u16* __restrict__ C, int M, int N, int K, int NC) {
  extern __shared__ __align__(16) char smem[];
  const int tid = threadIdx.x;
  const int l = tid & 63;
  const int w = tid >> 6;
  const int wr = w >> 1, wc = w & 1;

  const int GX = gridDim.x;
  int wg = blockIdx.y * GX + blockIdx.x;
  const int nwg = GX * gridDim.y;
  wg = (wg & 7) * (nwg >> 3) + (wg >> 3);
  const int bn0 = (wg % GX) * 128;
  const int bm0 = (wg / GX) * 256;

  const int NT = K >> 6;
  const int NI = NT >> 1;

  const int row_l = l & 15;
  const int kl = (l >> 4) * 8;
  const int xr = (row_l & 7) << 3;
  const int aoff0 = row_l * 128 + (((0 * 32 + kl) ^ xr) * 2);
  const int aoff1 = row_l * 128 + (((1 * 32 + kl) ^ xr) * 2);
  const int Abase_rd = (wr >> 1) * 16384 + (wr & 1) * 8192;
  const int Bbase_rd = 32768 + wc * 8192;

  const int srow = w * 16 + (l >> 3);
  const int scol = ((l & 7) ^ ((l >> 3) & 7)) << 3;
  const int ldsw = w * 2048;

  enum { c0A0 = 0, c0A1 = 16384, c0B = 32768,
         c1A0 = 49152, c1A1 = 65536, c1B = 81920 };

  STG(BT, bn0, 0, c0B);
  STG(A, bm0, 0, c0A0);
  STG(A, bm0 + 128, 0, c0A1);
  STG(BT, bn0, 1, c1B);
  VMC(2);
  BARRIER;

  f32x4 acc[4][4];
#pragma unroll
  for (int i = 0; i < 4; ++i)
#pragma unroll
    for (int j = 0; j < 4; ++j) acc[i][j] = f32x4{0.f, 0.f, 0.f, 0.f};
  s16x8 af[2][2], bf0[2][2], bf1[2][2];

  for (int j = 0; j < NI; ++j) {
    const int t1 = 2 * j + 1;
    int t2 = 2 * j + 2; if (t2 >= NT) t2 = 0;
    int t3 = 2 * j + 3; if (t3 >= NT) t3 = 1;
    // P1
    LDA2(0, 0); LDB(bf0, 0, 0);
    STG(A, bm0, t1, c1A0);
    BARRIER; MFMAQ2(0, 0, bf0); BARRIER;
    // P2
    LDB(bf1, 0, 1);
    STG(A, bm0 + 128, t1, c1A1);
    BARRIER; MFMAQ2(0, 1, bf1); BARRIER;
    // P3
    LDA2(0, 1);
    STG(BT, bn0, t2, c0B);
    BARRIER; MFMAQ2(1, 0, bf0); BARRIER;
    // P4
    STG(A, bm0, t2, c0A0);
    VMC(4);
    BARRIER; MFMAQ2(1, 1, bf1); BARRIER;
    // P5
    LDA2(49152, 0); LDB(bf0, 49152, 0);
    STG(A, bm0 + 128, t2, c0A1);
    BARRIER; MFMAQ2(0, 0, bf0); BARRIER;
    // P6
    LDB(bf1, 49152, 1);
    BARRIER; MFMAQ2(0, 1, bf1); BARRIER;
    // P7
    LDA2(49152, 1);
    STG(BT, bn0, t3, c1B);
    BARRIER; MFMAQ2(1, 0, bf0); BARRIER;
    // P8
    VMC(2);
    BARRIER; MFMAQ2(1, 1, bf1); BARRIER;
  }

  const int r0 = bm0 + wr * 64 + ((l >> 4) << 2);
#pragma unroll
  for (int fi = 0; fi < 4; ++fi) {
#pragma unroll
    for (int fj = 0; fj < 4; ++fj) {
      const int ocol = bn0 + wc * 64 + fj * 16 + (l & 15);
      const float bv = bias[ocol];
      const int row = r0 + fi * 16;
#pragma unroll
      for (int r = 0; r < 4; ++r) {
        float v = acc[fi][fj][r] + bv;
        if constexpr (EPI == 1) v += b2f(resid[(size_t)(row + r) * NC + ocol]);
        if constexpr (EPI == 2) v = 0.5f * v * (1.f + erff(v * 0.70710678118654752f));
        if constexpr (EPI == 3) v = tanhf(v);
        C[(size_t)(row + r) * NC + ocol] = f2b(v);
      }
    }
  }
}

// ---------------------------------------------------------------------------
// transpose helpers (f32 -> bf16)
// ---------------------------------------------------------------------------
DI void ttile(const float* in, u16* out, int R, int C, int r0, int c0, int t) {
  __shared__ u16 tile[32][33];
  const int lr = t >> 3;
  const int lc = (t & 7) * 4;
  f32x4 v = *(const f32x4*)(in + (size_t)(r0 + lr) * C + c0 + lc);
#pragma unroll
  for (int j = 0; j < 4; ++j) tile[lr][lc + j] = f2b(v[j]);
  __syncthreads();
  u16x4 o;
#pragma unroll
  for (int j = 0; j < 4; ++j) o[j] = tile[lc + j][lr];
  *(u16x4*)(out + (size_t)(c0 + lr) * R + r0 + lc) = o;
}

__global__ __launch_bounds__(256) void transpose_cvt(
    const float* __restrict__ in, u16* __restrict__ out, int R, int C) {
  ttile(in, out, R, C, blockIdx.y * 32, blockIdx.x * 32, threadIdx.x);
}

__global__ __launch_bounds__(256) void transpose4sq(
    const float* s0, const float* s1, const float* s2, const float* s3,
    u16* d0, u16* d1, u16* d2, u16* d3) {
  const int z = blockIdx.z;
  const float* in = z == 0 ? s0 : z == 1 ? s1 : z == 2 ? s2 : s3;
  u16* out = z == 0 ? d0 : z == 1 ? d1 : z == 2 ? d2 : d3;
  ttile(in, out, 1024, 1024, blockIdx.y * 32, blockIdx.x * 32, threadIdx.x);
}

__global__ __launch_bounds__(256) void transpose_io(
    const float* si, u16* di, const float* so, u16* dout) {
  if (blockIdx.z == 0) {
    ttile(si, di, 1024, 4096, blockIdx.y * 32, blockIdx.x * 32, threadIdx.x);
  } else {
    ttile(so, dout, 4096, 1024, blockIdx.x * 32, blockIdx.y * 32, threadIdx.x);
  }
}

__global__ __launch_bounds__(256) void cvt_k(
    const float* __restrict__ in, u16* __restrict__ out) {
  const size_t i = ((size_t)blockIdx.x * 256 + threadIdx.x) * 8;
  f32x4 a = *(const f32x4*)(in + i);
  f32x4 b = *(const f32x4*)(in + i + 4);
  u16x8 o;
#pragma unroll
  for (int j = 0; j < 4; ++j) o[j] = f2b(a[j]);
#pragma unroll
  for (int j = 0; j < 4; ++j) o[4 + j] = f2b(b[j]);
  *(u16x8*)(out + i) = o;
}

// ---------------------------------------------------------------------------
// Fused additive attention (r11, proven): gq -> gk -> u = q*gk per (b,h).
// ---------------------------------------------------------------------------
__global__ __launch_bounds__(128) void attn_fused(
    const u16* __restrict__ q, const u16* __restrict__ k,
    const float* __restrict__ hwq, const float* __restrict__ hwk,
    u16* __restrict__ u) {
  const int bh = blockIdx.x;
  const int b = bh >> 4, h = bh & 15;
  const int tid = threadIdx.x;
  const int lane = tid & 63, wv = tid >> 6;
  const int d = tid & 63, half = tid >> 6;
  __shared__ float hw[64];
  __shared__ float gqs[64];
  __shared__ float gks[64];
  __shared__ float ex[128];
  __shared__ float part[64];
  __shared__ float xw[4];

  // ---- phase 1: gq ----
  if (tid < 64) hw[tid] = hwq[h * 64 + tid];
  __syncthreads();
  const u16* qrow = q + ((size_t)(b * 128 + tid)) * Dc + h * 64;
  float s = 0.f;
#pragma unroll
  for (int c = 0; c < 8; ++c) {
    u16x8 v = *(const u16x8*)(qrow + c * 8);
#pragma unroll
    for (int j = 0; j < 8; ++j) s += b2f(v[j]) * hw[c * 8 + j];
  }
  s *= 0.125f;
  float m = s;
  for (int o = 32; o; o >>= 1) m = fmaxf(m, __shfl_xor(m, o));
  if (lane == 0) xw[wv] = m;
  __syncthreads();
  m = fmaxf(xw[0], xw[1]);
  float e = __expf(s - m);
  ex[tid] = e;
  float sm = e;
  for (int o = 32; o; o >>= 1) sm += __shfl_xor(sm, o);
  if (lane == 0) xw[2 + wv] = sm;
  __syncthreads();
  float sum = xw[2] + xw[3];
  {
    const u16* colp = q + ((size_t)(b * 128 + half * 64)) * Dc + h * 64 + d;
    float acc = 0.f;
    for (int t = 0; t < 64; ++t) acc += ex[half * 64 + t] * b2f(colp[(size_t)t * Dc]);
    if (half == 0) part[d] = acc;
    __syncthreads();
    if (half == 1) gqs[d] = (part[d] + acc) / sum;
  }
  __syncthreads();

  // ---- phase 2: gk ----
  if (tid < 64) hw[tid] = hwk[h * 64 + tid];
  __syncthreads();
  const u16* krow = k + ((size_t)(b * 128 + tid)) * Dc + h * 64;
  s = 0.f;
#pragma unroll
  for (int c = 0; c < 8; ++c) {
    u16x8 v = *(const u16x8*)(krow + c * 8);
#pragma unroll
    for (int j = 0; j < 8; ++j) s += b2f(v[j]) * gqs[c * 8 + j] * hw[c * 8 + j];
  }
  s *= 0.125f;
  m = s;
  for (int o = 32; o; o >>= 1) m = fmaxf(m, __shfl_xor(m, o));
  if (lane == 0) xw[wv] = m;
  __syncthreads();
  m = fmaxf(xw[0], xw[1]);
  e = __expf(s - m);
  ex[tid] = e;
  sm = e;
  for (int o = 32; o; o >>= 1) sm += __shfl_xor(sm, o);
  if (lane == 0) xw[2 + wv] = sm;
  __syncthreads();
  sum = xw[2] + xw[3];
  {
    const u16* colp = k + ((size_t)(b * 128 + half * 64)) * Dc + h * 64 + d;
    float acc = 0.f;
    for (int t = 0; t < 64; ++t) acc += ex[half * 64 + t] * b2f(colp[(size_t)t * Dc]);
    acc *= gqs[d];
    if (half == 0) part[d] = acc;
    __syncthreads();
    if (half == 1) gks[d] = (part[d] + acc) / sum;
  }
  __syncthreads();

  // ---- phase 3: u = q * gk ----
  const float g = gks[d];
  const u16* qp = q + (size_t)b * 128 * Dc + h * 64 + d;
  u16* up = u + (size_t)b * 128 * Dc + h * 64 + d;
  for (int t = half; t < 128; t += 2) {
    up[(size_t)t * Dc] = f2b(b2f(qp[(size_t)t * Dc]) * g);
  }
}

__global__ __launch_bounds__(256) void ln_k(
    const u16* __restrict__ in, const float* __restrict__ g,
    const float* __restrict__ bta, u16* __restrict__ out) {
  const int row = blockIdx.x, tid = threadIdx.x;
  const int lane = tid & 63, wave = tid >> 6;
  __shared__ float red[8];
  const u16* p = in + (size_t)row * Dc + tid * 4;
  u16x4 v = *(const u16x4*)p;
  float x[4];
  float s = 0.f, sq = 0.f;
#pragma unroll
  for (int j = 0; j < 4; ++j) {
    x[j] = b2f(v[j]);
    s += x[j];
    sq += x[j] * x[j];
  }
  for (int o = 32; o; o >>= 1) {
    s += __shfl_down(s, o);
    sq += __shfl_down(sq, o);
  }
  if (lane == 0) {
    red[wave] = s;
    red[4 + wave] = sq;
  }
  __syncthreads();
  s = red[0] + red[1] + red[2] + red[3];
  sq = red[4] + red[5] + red[6] + red[7];
  const float mean = s * (1.f / 1024.f);
  const float var = sq * (1.f / 1024.f) - mean * mean;
  const float rs = rsqrtf(var + 1e-12f);
  f32x4 gv = *(const f32x4*)(g + tid * 4);
  f32x4 bv = *(const f32x4*)(bta + tid * 4);
  u16x4 o;
#pragma unroll
  for (int j = 0; j < 4; ++j) o[j] = f2b((x[j] - mean) * rs * gv[j] + bv[j]);
  *(u16x4*)(out + (size_t)row * Dc + tid * 4) = o;
}

__global__ __launch_bounds__(256) void pool_k(
    const u16* __restrict__ s1, const float* __restrict__ pq,
    const u16* __restrict__ h, float* __restrict__ out) {
  const int b = blockIdx.x, tid = threadIdx.x;
  __shared__ float pqs[1024];
  __shared__ float sc[128];
  __shared__ float ex[128];
  for (int i = tid; i < 1024; i += 256) pqs[i] = pq[i];
  __syncthreads();
  if (tid < 128) {
    const u16* row = s1 + ((size_t)(b * 128 + tid)) * Dc;
    float s = 0.f;
    for (int c = 0; c < 128; ++c) {
      u16x8 v = *(const u16x8*)(row + c * 8);
#pragma unroll
      for (int j = 0; j < 8; ++j) s += b2f(v[j]) * pqs[c * 8 + j];
    }
    sc[tid] = s;
  }
  __syncthreads();
  float m = -1e30f;
  for (int t = 0; t < 128; ++t) m = fmaxf(m, sc[t]);
  if (tid < 128) ex[tid] = __expf(sc[tid] - m);
  __syncthreads();
  float sum = 0.f;
  for (int t = 0; t < 128; ++t) sum += ex[t];
  const int d0 = tid * 4;
  float acc[4] = {0.f, 0.f, 0.f, 0.f};
  for (int n = 0; n < 128; ++n) {
    const float w = ex[n];
    u16x4 v = *(const u16x4*)(h + ((size_t)(b * 128 + n)) * Dc + d0);
#pragma unroll
    for (int j = 0; j < 4; ++j) acc[j] += w * b2f(v[j]);
  }
  const float inv = 1.f / sum;
  f32x4 o;
#pragma unroll
  for (int j = 0; j < 4; ++j) o[j] = acc[j] * inv;
  *(f32x4*)(out + b * Dc + d0) = o;
}

// ---------------------------------------------------------------------------
extern "C" void kernel_launch(void* const* d_in, const int* in_sizes, int n_in,
                              void* d_out, int out_size, void* d_ws, size_t ws_size,
                              hipStream_t stream) {
  const float* x = (const float*)d_in[0];
  const float* wq_w = (const float*)d_in[1];
  const float* wq_b = (const float*)d_in[2];
  const float* wk_w = (const float*)d_in[3];
  const float* wk_b = (const float*)d_in[4];
  const float* hwq = (const float*)d_in[5];
  const float* hwk = (const float*)d_in[6];
  const float* tr_w = (const float*)d_in[7];
  const float* tr_b = (const float*)d_in[8];
  const float* so_w = (const float*)d_in[9];
  const float* so_b = (const float*)d_in[10];
  const float* ln1g = (const float*)d_in[11];
  const float* ln1b = (const float*)d_in[12];
  const float* int_w = (const float*)d_in[13];
  const float* int_b = (const float*)d_in[14];
  const float* out_w = (const float*)d_in[15];
  const float* out_b = (const float*)d_in[16];
  const float* ln2g = (const float*)d_in[17];
  const float* ln2b = (const float*)d_in[18];
  const float* pool_w = (const float*)d_in[19];
  const float* pool_b = (const float*)d_in[20];
  const float* pool_q = (const float*)d_in[21];

  char* w = (char*)d_ws;
  auto alloc = [&](size_t bytes) {
    char* p = w;
    w += (bytes + 255) & ~(size_t)255;
    return p;
  };
  u16* wTqk = (u16*)alloc((size_t)2 * Dc * Dc * 2);
  u16* wTtr = (u16*)alloc((size_t)Dc * Dc * 2);
  u16* wTso = (u16*)alloc((size_t)Dc * Dc * 2);
  u16* wTint = (u16*)alloc((size_t)Dc * Ic * 2);
  u16* wTout = (u16*)alloc((size_t)Dc * Ic * 2);
  u16* wTpool = (u16*)alloc((size_t)Dc * Dc * 2);
  u16* qb = (u16*)alloc((size_t)Mrows * Dc * 2);
  u16* kb = (u16*)alloc((size_t)Mrows * Dc * 2);
  u16* ab = (u16*)alloc((size_t)Mrows * Dc * 2);
  u16* tb = (u16*)alloc((size_t)Mrows * Dc * 2);
  u16* xc = (u16*)alloc((size_t)Mrows * Dc * 2);
  u16* hb = (u16*)alloc((size_t)Mrows * Ic * 2);
  if ((size_t)(w - (char*)d_ws) > ws_size) return;

  static constexpr size_t LDSB = 131072;
  static constexpr size_t LDSB2 = 98304;
  hipFuncSetAttribute((const void*)gemm256<0, true>, hipFuncAttributeMaxDynamicSharedMemorySize, LDSB);
  hipFuncSetAttribute((const void*)gemm256<2, false>, hipFuncAttributeMaxDynamicSharedMemorySize, LDSB);
  hipFuncSetAttribute((const void*)gemm128n<0>, hipFuncAttributeMaxDynamicSharedMemorySize, LDSB2);
  hipFuncSetAttribute((const void*)gemm128n<1>, hipFuncAttributeMaxDynamicSharedMemorySize, LDSB2);
  hipFuncSetAttribute((const void*)gemm128n<3>, hipFuncAttributeMaxDynamicSharedMemorySize, LDSB2);

  const dim3 blk(256);
  const dim3 blkG(512);
  const dim3 gT1(Dc / 32, Dc / 32);
  const dim3 gT4(Dc / 32, Dc / 32, 4);
  const dim3 gTio(Ic / 32, Dc / 32, 2);
  const dim3 gQK(2048 / 256, Mrows / 256);  // (8,32) = 256 blocks
  const dim3 gNi(Ic / 256, Mrows / 256);    // (16,32) = 512 blocks
  const dim3 gO(Dc / 128, Mrows / 256);     // (8,32) = 256 blocks

  cvt_k<<<(Mrows * Dc) / (256 * 8), blk, 0, stream>>>(x, xc);

  for (int i = 0; i < Lc; ++i) {
    transpose4sq<<<gT4, blk, 0, stream>>>(
        wq_w + (size_t)i * Dc * Dc, wk_w + (size_t)i * Dc * Dc,
        tr_w + (size_t)i * Dc * Dc, so_w + (size_t)i * Dc * Dc,
        wTqk, wTqk + (size_t)Dc * Dc, wTtr, wTso);
    transpose_io<<<gTio, blk, 0, stream>>>(
        int_w + (size_t)i * Dc * Ic, wTint, out_w + (size_t)i * Ic * Dc, wTout);

    // q | k = x @ [Wq ; Wk] (fused N=2048, split outputs)
    gemm256<0, true><<<gQK, blkG, LDSB, stream>>>(xc, wTqk, wq_b + i * Dc, wk_b + i * Dc,
                                                  nullptr, qb, kb, Mrows, 2048, Dc, Dc);
    // gq -> gk -> u = q*gk, one dispatch; u written into kb (head-local cols)
    attn_fused<<<Bc * Hc, 128, 0, stream>>>(qb, kb, hwq + i * Hc * HDc,
                                            hwk + i * Hc * HDc, kb);
    // attn_out = u@tr + tr_b + q
    gemm128n<1><<<gO, blkG, LDSB2, stream>>>(kb, wTtr, tr_b + i * Dc, qb, tb, Mrows, Dc, Dc, Dc);
    // t2 = attn_out@so + so_b ; a = LN1(t2)
    gemm128n<0><<<gO, blkG, LDSB2, stream>>>(tb, wTso, so_b + i * Dc, nullptr, kb, Mrows, Dc, Dc, Dc);
    ln_k<<<Mrows, blk, 0, stream>>>(kb, ln1g + i * Dc, ln1b + i * Dc, ab);
    // h = gelu(a@int + int_b)
    gemm256<2, false><<<gNi, blkG, LDSB, stream>>>(ab, wTint, int_b + i * Ic, nullptr,
                                                   nullptr, hb, nullptr, Mrows, Ic, Dc, Ic);
    // o+a = h@out + out_b + a ; x = LN2
    gemm128n<1><<<gO, blkG, LDSB2, stream>>>(hb, wTout, out_b + i * Dc, ab, tb, Mrows, Dc, Ic, Dc);
    ln_k<<<Mrows, blk, 0, stream>>>(tb, ln2g + i * Dc, ln2b + i * Dc, xc);
  }

  transpose_cvt<<<gT1, blk, 0, stream>>>(pool_w, wTpool, Dc, Dc);
  gemm128n<3><<<gO, blkG, LDSB2, stream>>>(xc, wTpool, pool_b, nullptr, tb, Mrows, Dc, Dc, Dc);
  pool_k<<<Bc, blk, 0, stream>>>(tb, pool_q, xc, (float*)d_out);
}

// Round 14
// 1207.403 us; speedup vs baseline: 1.0498x; 1.0124x over previous
//
#include <hip/hip_runtime.h>
#include <hip/hip_bf16.h>
#include <math.h>

typedef unsigned short u16;
typedef __attribute__((ext_vector_type(4))) unsigned short u16x4;
typedef __attribute__((ext_vector_type(8))) unsigned short u16x8;
typedef __attribute__((ext_vector_type(8))) short s16x8;
typedef __attribute__((ext_vector_type(4))) float f32x4;

typedef const __attribute__((address_space(1))) void* gas_t;
typedef __attribute__((address_space(3))) void* las_t;

#define DI __device__ __forceinline__

static constexpr int Bc = 64, Nc = 128, Dc = 1024, Hc = 16, HDc = 64, Ic = 4096, Lc = 4;
static constexpr int Mrows = Bc * Nc; // 8192

DI float b2f(u16 u) { union { unsigned i; float f; } x; x.i = ((unsigned)u) << 16; return x.f; }
DI u16 f2b(float f) {
  union { float f; unsigned i; } x; x.f = f;
  unsigned r = x.i + 0x7FFF + ((x.i >> 16) & 1);
  return (u16)(r >> 16);
}

#define BARRIER do { asm volatile("" ::: "memory"); __builtin_amdgcn_s_barrier(); asm volatile("" ::: "memory"); } while (0)
#define VMC(N) asm volatile("s_waitcnt vmcnt(" #N ")" ::: "memory")

// stage a (waves*16)-row half-tile: per wave 16 rows, 2 glls x 64 lanes x 16B
#define STG(PTR, ROW0, T, SLOT) do { \
    const u16* _s = (PTR) + (size_t)((ROW0) + srow) * K + (((T) << 6) + scol); \
    __builtin_amdgcn_global_load_lds((gas_t)_s, (las_t)(smem + (SLOT) + ldsw), 16, 0, 0); \
    __builtin_amdgcn_global_load_lds((gas_t)(_s + ((size_t)K << 3)), (las_t)(smem + (SLOT) + ldsw + 1024), 16, 0, 0); \
  } while (0)

// ===========================================================================
// 256x256 8-phase GEMM, BK=64, 8 waves (2M x 4N). LDS 128 KiB. (r11/r13 best)
// ===========================================================================
#define LDA(BUFB, RH) do { \
    _Pragma("unroll") \
    for (int mi = 0; mi < 4; ++mi) { \
      af[mi][0] = *(const s16x8*)(smem + (BUFB) + Abase_rd + (RH) * 8192 + mi * 2048 + aoff0); \
      af[mi][1] = *(const s16x8*)(smem + (BUFB) + Abase_rd + (RH) * 8192 + mi * 2048 + aoff1); \
    } } while (0)

#define LDB(DST, BUFB, CH) do { \
    _Pragma("unroll") \
    for (int nj = 0; nj < 2; ++nj) { \
      DST[nj][0] = *(const s16x8*)(smem + (BUFB) + Bbase_rd + (CH) * 4096 + nj * 2048 + aoff0); \
      DST[nj][1] = *(const s16x8*)(smem + (BUFB) + Bbase_rd + (CH) * 4096 + nj * 2048 + aoff1); \
    } } while (0)

#define MFMAQ(RH, CH, BF) do { \
    __builtin_amdgcn_s_setprio(1); \
    _Pragma("unroll") \
    for (int kk = 0; kk < 2; ++kk) \
      _Pragma("unroll") \
      for (int mi = 0; mi < 4; ++mi) \
        _Pragma("unroll") \
        for (int nj = 0; nj < 2; ++nj) \
          acc[(RH) * 4 + mi][(CH) * 2 + nj] = __builtin_amdgcn_mfma_f32_16x16x32_bf16( \
              af[mi][kk], BF[nj][kk], acc[(RH) * 4 + mi][(CH) * 2 + nj], 0, 0, 0); \
    __builtin_amdgcn_s_setprio(0); \
  } while (0)

template <int EPI, bool SPLIT>
__global__ __launch_bounds__(512, 2) void gemm256(
    const u16* __restrict__ A, const u16* __restrict__ BT,
    const float* __restrict__ bias, const float* __restrict__ bias2,
    const u16* __restrict__ resid, u16* __restrict__ C, u16* __restrict__ C2,
    int M, int N, int K, int NC) {
  extern __shared__ __align__(16) char smem[];
  const int tid = threadIdx.x;
  const int l = tid & 63;
  const int w = tid >> 6;
  const int wr = w >> 2, wc = w & 3;

  const int GX = gridDim.x;
  int wg = blockIdx.y * GX + blockIdx.x;
  const int nwg = GX * gridDim.y;
  wg = (wg & 7) * (nwg >> 3) + (wg >> 3);
  const int bn0 = (wg % GX) * 256;
  const int bm0 = (wg / GX) * 256;

  const int NT = K >> 6;
  const int NI = NT >> 1;

  const int row_l = l & 15;
  const int kl = (l >> 4) * 8;
  const int xr = (row_l & 7) << 3;
  const int aoff0 = row_l * 128 + (((0 * 32 + kl) ^ xr) * 2);
  const int aoff1 = row_l * 128 + (((1 * 32 + kl) ^ xr) * 2);
  const int Abase_rd = wr * 16384;
  const int Bbase_rd = 32768 + (wc >> 1) * 16384 + (wc & 1) * 8192;

  const int srow = w * 16 + (l >> 3);
  const int scol = ((l & 7) ^ ((l >> 3) & 7)) << 3;
  const int ldsw = w * 2048;

  enum { b0A0 = 0, b0A1 = 16384, b0B0 = 32768, b0B1 = 49152,
         b1A0 = 65536, b1A1 = 81920, b1B0 = 98304, b1B1 = 114688 };

  STG(BT, bn0, 0, b0B0);
  STG(BT, bn0 + 128, 0, b0B1);
  STG(A, bm0, 0, b0A0);
  STG(A, bm0 + 128, 0, b0A1);
  STG(BT, bn0, 1, b1B0);
  STG(BT, bn0 + 128, 1, b1B1);
  VMC(4);
  BARRIER;

  f32x4 acc[8][4];
#pragma unroll
  for (int i = 0; i < 8; ++i)
#pragma unroll
    for (int j = 0; j < 4; ++j) acc[i][j] = f32x4{0.f, 0.f, 0.f, 0.f};
  s16x8 af[4][2], bf0[2][2], bf1[2][2];

  for (int j = 0; j < NI; ++j) {
    const int t1 = 2 * j + 1;
    int t2 = 2 * j + 2; if (t2 >= NT) t2 = 0;
    int t3 = 2 * j + 3; if (t3 >= NT) t3 = 1;
    // P1
    LDA(0, 0); LDB(bf0, 0, 0);
    STG(A, bm0, t1, b1A0);
    BARRIER; MFMAQ(0, 0, bf0); BARRIER;
    // P2
    LDB(bf1, 0, 1);
    STG(A, bm0 + 128, t1, b1A1);
    BARRIER; MFMAQ(0, 1, bf1); BARRIER;
    // P3
    LDA(0, 1);
    STG(BT, bn0, t2, b0B0);
    BARRIER; MFMAQ(1, 0, bf0); BARRIER;
    // P4
    STG(BT, bn0 + 128, t2, b0B1);
    STG(A, bm0, t2, b0A0);
    VMC(6);
    BARRIER; MFMAQ(1, 1, bf1); BARRIER;
    // P5
    LDA(65536, 0); LDB(bf0, 65536, 0);
    STG(A, bm0 + 128, t2, b0A1);
    BARRIER; MFMAQ(0, 0, bf0); BARRIER;
    // P6
    LDB(bf1, 65536, 1);
    BARRIER; MFMAQ(0, 1, bf1); BARRIER;
    // P7
    LDA(65536, 1);
    STG(BT, bn0, t3, b1B0);
    BARRIER; MFMAQ(1, 0, bf0); BARRIER;
    // P8
    STG(BT, bn0 + 128, t3, b1B1);
    VMC(4);
    BARRIER; MFMAQ(1, 1, bf1); BARRIER;
  }

  u16* Cout = C;
  const float* bi = bias;
  int cb = bn0;
  if (SPLIT) {
    const int half = N >> 1;
    if (bn0 >= half) { Cout = C2; bi = bias2; cb = bn0 - half; }
  }
  const int r0 = bm0 + wr * 128 + ((l >> 4) << 2);
#pragma unroll
  for (int fi = 0; fi < 8; ++fi) {
#pragma unroll
    for (int fj = 0; fj < 4; ++fj) {
      const int ocol = cb + wc * 64 + fj * 16 + (l & 15);
      const float bv = bi[ocol];
      const int row = r0 + fi * 16;
#pragma unroll
      for (int r = 0; r < 4; ++r) {
        float v = acc[fi][fj][r] + bv;
        if constexpr (EPI == 1) v += b2f(resid[(size_t)(row + r) * NC + ocol]);
        if constexpr (EPI == 2) v = 0.5f * v * (1.f + erff(v * 0.70710678118654752f));
        if constexpr (EPI == 3) v = tanhf(v);
        Cout[(size_t)(row + r) * NC + ocol] = f2b(v);
      }
    }
  }
}

// ===========================================================================
// 256x128 8-phase GEMM, BK=64, 8 waves (4M x 2N), LDS 96 KiB. (r11/r13 best)
// ===========================================================================
#define LDA2(BUFB, RH) do { \
    _Pragma("unroll") \
    for (int mi = 0; mi < 2; ++mi) { \
      af[mi][0] = *(const s16x8*)(smem + (BUFB) + Abase_rd + ((RH) * 2 + mi) * 2048 + aoff0); \
      af[mi][1] = *(const s16x8*)(smem + (BUFB) + Abase_rd + ((RH) * 2 + mi) * 2048 + aoff1); \
    } } while (0)

#define MFMAQ2(RH, CH, BF) do { \
    __builtin_amdgcn_s_setprio(1); \
    _Pragma("unroll") \
    for (int kk = 0; kk < 2; ++kk) \
      _Pragma("unroll") \
      for (int mi = 0; mi < 2; ++mi) \
        _Pragma("unroll") \
        for (int nj = 0; nj < 2; ++nj) \
          acc[(RH) * 2 + mi][(CH) * 2 + nj] = __builtin_amdgcn_mfma_f32_16x16x32_bf16( \
              af[mi][kk], BF[nj][kk], acc[(RH) * 2 + mi][(CH) * 2 + nj], 0, 0, 0); \
    __builtin_amdgcn_s_setprio(0); \
  } while (0)

template <int EPI>
__global__ __launch_bounds__(512, 2) void gemm128n(
    const u16* __restrict__ A, const u16* __restrict__ BT,
    const float* __restrict__ bias, const u16* __restrict__ resid,
    u16* __restrict__ C, int M, int N, int K, int NC) {
  extern __shared__ __align__(16) char smem[];
  const int tid = threadIdx.x;
  const int l = tid & 63;
  const int w = tid >> 6;
  const int wr = w >> 1, wc = w & 1;

  const int GX = gridDim.x;
  int wg = blockIdx.y * GX + blockIdx.x;
  const int nwg = GX * gridDim.y;
  wg = (wg & 7) * (nwg >> 3) + (wg >> 3);
  const int bn0 = (wg % GX) * 128;
  const int bm0 = (wg / GX) * 256;

  const int NT = K >> 6;
  const int NI = NT >> 1;

  const int row_l = l & 15;
  const int kl = (l >> 4) * 8;
  const int xr = (row_l & 7) << 3;
  const int aoff0 = row_l * 128 + (((0 * 32 + kl) ^ xr) * 2);
  const int aoff1 = row_l * 128 + (((1 * 32 + kl) ^ xr) * 2);
  const int Abase_rd = (wr >> 1) * 16384 + (wr & 1) * 8192;
  const int Bbase_rd = 32768 + wc * 8192;

  const int srow = w * 16 + (l >> 3);
  const int scol = ((l & 7) ^ ((l >> 3) & 7)) << 3;
  const int ldsw = w * 2048;

  enum { c0A0 = 0, c0A1 = 16384, c0B = 32768,
         c1A0 = 49152, c1A1 = 65536, c1B = 81920 };

  STG(BT, bn0, 0, c0B);
  STG(A, bm0, 0, c0A0);
  STG(A, bm0 + 128, 0, c0A1);
  STG(BT, bn0, 1, c1B);
  VMC(2);
  BARRIER;

  f32x4 acc[4][4];
#pragma unroll
  for (int i = 0; i < 4; ++i)
#pragma unroll
    for (int j = 0; j < 4; ++j) acc[i][j] = f32x4{0.f, 0.f, 0.f, 0.f};
  s16x8 af[2][2], bf0[2][2], bf1[2][2];

  for (int j = 0; j < NI; ++j) {
    const int t1 = 2 * j + 1;
    int t2 = 2 * j + 2; if (t2 >= NT) t2 = 0;
    int t3 = 2 * j + 3; if (t3 >= NT) t3 = 1;
    // P1
    LDA2(0, 0); LDB(bf0, 0, 0);
    STG(A, bm0, t1, c1A0);
    BARRIER; MFMAQ2(0, 0, bf0); BARRIER;
    // P2
    LDB(bf1, 0, 1);
    STG(A, bm0 + 128, t1, c1A1);
    BARRIER; MFMAQ2(0, 1, bf1); BARRIER;
    // P3
    LDA2(0, 1);
    STG(BT, bn0, t2, c0B);
    BARRIER; MFMAQ2(1, 0, bf0); BARRIER;
    // P4
    STG(A, bm0, t2, c0A0);
    VMC(4);
    BARRIER; MFMAQ2(1, 1, bf1); BARRIER;
    // P5
    LDA2(49152, 0); LDB(bf0, 49152, 0);
    STG(A, bm0 + 128, t2, c0A1);
    BARRIER; MFMAQ2(0, 0, bf0); BARRIER;
    // P6
    LDB(bf1, 49152, 1);
    BARRIER; MFMAQ2(0, 1, bf1); BARRIER;
    // P7
    LDA2(49152, 1);
    STG(BT, bn0, t3, c1B);
    BARRIER; MFMAQ2(1, 0, bf0); BARRIER;
    // P8
    VMC(2);
    BARRIER; MFMAQ2(1, 1, bf1); BARRIER;
  }

  const int r0 = bm0 + wr * 64 + ((l >> 4) << 2);
#pragma unroll
  for (int fi = 0; fi < 4; ++fi) {
#pragma unroll
    for (int fj = 0; fj < 4; ++fj) {
      const int ocol = bn0 + wc * 64 + fj * 16 + (l & 15);
      const float bv = bias[ocol];
      const int row = r0 + fi * 16;
#pragma unroll
      for (int r = 0; r < 4; ++r) {
        float v = acc[fi][fj][r] + bv;
        if constexpr (EPI == 1) v += b2f(resid[(size_t)(row + r) * NC + ocol]);
        if constexpr (EPI == 2) v = 0.5f * v * (1.f + erff(v * 0.70710678118654752f));
        if constexpr (EPI == 3) v = tanhf(v);
        C[(size_t)(row + r) * NC + ocol] = f2b(v);
      }
    }
  }
}

// ---------------------------------------------------------------------------
// transpose helpers (f32 -> bf16)
// ---------------------------------------------------------------------------
DI void ttile(const float* in, u16* out, int R, int C, int r0, int c0, int t) {
  __shared__ u16 tile[32][33];
  const int lr = t >> 3;
  const int lc = (t & 7) * 4;
  f32x4 v = *(const f32x4*)(in + (size_t)(r0 + lr) * C + c0 + lc);
#pragma unroll
  for (int j = 0; j < 4; ++j) tile[lr][lc + j] = f2b(v[j]);
  __syncthreads();
  u16x4 o;
#pragma unroll
  for (int j = 0; j < 4; ++j) o[j] = tile[lc + j][lr];
  *(u16x4*)(out + (size_t)(c0 + lr) * R + r0 + lc) = o;
}

__global__ __launch_bounds__(256) void transpose_cvt(
    const float* __restrict__ in, u16* __restrict__ out, int R, int C) {
  ttile(in, out, R, C, blockIdx.y * 32, blockIdx.x * 32, threadIdx.x);
}

__global__ __launch_bounds__(256) void transpose4sq(
    const float* s0, const float* s1, const float* s2, const float* s3,
    u16* d0, u16* d1, u16* d2, u16* d3) {
  const int z = blockIdx.z;
  const float* in = z == 0 ? s0 : z == 1 ? s1 : z == 2 ? s2 : s3;
  u16* out = z == 0 ? d0 : z == 1 ? d1 : z == 2 ? d2 : d3;
  ttile(in, out, 1024, 1024, blockIdx.y * 32, blockIdx.x * 32, threadIdx.x);
}

__global__ __launch_bounds__(256) void transpose_io(
    const float* si, u16* di, const float* so, u16* dout) {
  if (blockIdx.z == 0) {
    ttile(si, di, 1024, 4096, blockIdx.y * 32, blockIdx.x * 32, threadIdx.x);
  } else {
    ttile(so, dout, 4096, 1024, blockIdx.x * 32, blockIdx.y * 32, threadIdx.x);
  }
}

__global__ __launch_bounds__(256) void cvt_k(
    const float* __restrict__ in, u16* __restrict__ out) {
  const size_t i = ((size_t)blockIdx.x * 256 + threadIdx.x) * 8;
  f32x4 a = *(const f32x4*)(in + i);
  f32x4 b = *(const f32x4*)(in + i + 4);
  u16x8 o;
#pragma unroll
  for (int j = 0; j < 4; ++j) o[j] = f2b(a[j]);
#pragma unroll
  for (int j = 0; j < 4; ++j) o[4 + j] = f2b(b[j]);
  *(u16x8*)(out + i) = o;
}

// ---------------------------------------------------------------------------
// Fused additive attention v2: LDS-tiled. Per (b,h) block:
//  - coalesced load of q/k head tiles (128x64 bf16) into LDS (8 thr/row)
//  - gq: row dot (LDS) -> softmax -> column reduce (LDS)
//  - gk: same on k*gq
//  - u = q*gk written with coalesced 16B stores (8 thr/row)
// Math order identical to v1 (bitwise-same results).
// ---------------------------------------------------------------------------
__global__ __launch_bounds__(128) void attn_fused(
    const u16* __restrict__ q, const u16* __restrict__ k,
    const float* __restrict__ hwq, const float* __restrict__ hwk,
    u16* __restrict__ u) {
  const int bh = blockIdx.x;
  const int b = bh >> 4, h = bh & 15;
  const int tid = threadIdx.x;
  const int lane = tid & 63, wv = tid >> 6;
  const int d = tid & 63, half = tid >> 6;
  __shared__ u16 qt[128][68];   // padded row stride (136 B) -> low bank aliasing
  __shared__ u16 kt[128][68];
  __shared__ float hw[64];
  __shared__ float gqs[64];
  __shared__ float gks[64];
  __shared__ float ex[128];
  __shared__ float part[64];
  __shared__ float xw[4];

  // ---- coalesced tile load: 8 threads per row (128B contiguous per row) ----
  const int rw8 = tid >> 3;
  const int cg8 = (tid & 7) * 8;
#pragma unroll
  for (int pass = 0; pass < 8; ++pass) {
    const int row = pass * 16 + rw8;
    const size_t off = (size_t)(b * 128 + row) * Dc + h * 64 + cg8;
    u16x8 vq = *(const u16x8*)(q + off);
    u16x8 vk = *(const u16x8*)(k + off);
    u16x4 q0{vq[0], vq[1], vq[2], vq[3]}, q1{vq[4], vq[5], vq[6], vq[7]};
    u16x4 k0{vk[0], vk[1], vk[2], vk[3]}, k1{vk[4], vk[5], vk[6], vk[7]};
    *(u16x4*)&qt[row][cg8] = q0;
    *(u16x4*)&qt[row][cg8 + 4] = q1;
    *(u16x4*)&kt[row][cg8] = k0;
    *(u16x4*)&kt[row][cg8 + 4] = k1;
  }
  if (tid < 64) hw[tid] = hwq[h * 64 + tid];
  __syncthreads();

  // ---- phase 1: gq ----
  float s = 0.f;
#pragma unroll
  for (int c = 0; c < 16; ++c) {
    u16x4 v = *(const u16x4*)&qt[tid][c * 4];
#pragma unroll
    for (int j = 0; j < 4; ++j) s += b2f(v[j]) * hw[c * 4 + j];
  }
  s *= 0.125f;
  float m = s;
  for (int o = 32; o; o >>= 1) m = fmaxf(m, __shfl_xor(m, o));
  if (lane == 0) xw[wv] = m;
  __syncthreads();
  m = fmaxf(xw[0], xw[1]);
  float e = __expf(s - m);
  ex[tid] = e;
  float sm = e;
  for (int o = 32; o; o >>= 1) sm += __shfl_xor(sm, o);
  if (lane == 0) xw[2 + wv] = sm;
  __syncthreads();
  float sum = xw[2] + xw[3];
  {
    float acc = 0.f;
    for (int t = 0; t < 64; ++t) acc += ex[half * 64 + t] * b2f(qt[half * 64 + t][d]);
    if (half == 0) part[d] = acc;
    __syncthreads();
    if (half == 1) gqs[d] = (part[d] + acc) / sum;
  }
  __syncthreads();

  // ---- phase 2: gk ----
  if (tid < 64) hw[tid] = hwk[h * 64 + tid];  // hw last read pre-barrier: safe
  __syncthreads();
  s = 0.f;
#pragma unroll
  for (int c = 0; c < 16; ++c) {
    u16x4 v = *(const u16x4*)&kt[tid][c * 4];
#pragma unroll
    for (int j = 0; j < 4; ++j) s += b2f(v[j]) * gqs[c * 4 + j] * hw[c * 4 + j];
  }
  s *= 0.125f;
  m = s;
  for (int o = 32; o; o >>= 1) m = fmaxf(m, __shfl_xor(m, o));
  if (lane == 0) xw[wv] = m;
  __syncthreads();
  m = fmaxf(xw[0], xw[1]);
  e = __expf(s - m);
  ex[tid] = e;
  sm = e;
  for (int o = 32; o; o >>= 1) sm += __shfl_xor(sm, o);
  if (lane == 0) xw[2 + wv] = sm;
  __syncthreads();
  sum = xw[2] + xw[3];
  {
    float acc = 0.f;
    for (int t = 0; t < 64; ++t) acc += ex[half * 64 + t] * b2f(kt[half * 64 + t][d]);
    acc *= gqs[d];
    if (half == 0) part[d] = acc;
    __syncthreads();
    if (half == 1) gks[d] = (part[d] + acc) / sum;
  }
  __syncthreads();

  // ---- phase 3: u = q * gk, coalesced 16B stores ----
#pragma unroll
  for (int pass = 0; pass < 8; ++pass) {
    const int row = pass * 16 + rw8;
    u16x4 a = *(const u16x4*)&qt[row][cg8];
    u16x4 bb = *(const u16x4*)&qt[row][cg8 + 4];
    u16x8 o;
#pragma unroll
    for (int j = 0; j < 4; ++j) o[j] = f2b(b2f(a[j]) * gks[cg8 + j]);
#pragma unroll
    for (int j = 0; j < 4; ++j) o[4 + j] = f2b(b2f(bb[j]) * gks[cg8 + 4 + j]);
    *(u16x8*)(u + (size_t)(b * 128 + row) * Dc + h * 64 + cg8) = o;
  }
}

__global__ __launch_bounds__(256) void ln_k(
    const u16* __restrict__ in, const float* __restrict__ g,
    const float* __restrict__ bta, u16* __restrict__ out) {
  const int row = blockIdx.x, tid = threadIdx.x;
  const int lane = tid & 63, wave = tid >> 6;
  __shared__ float red[8];
  const u16* p = in + (size_t)row * Dc + tid * 4;
  u16x4 v = *(const u16x4*)p;
  float x[4];
  float s = 0.f, sq = 0.f;
#pragma unroll
  for (int j = 0; j < 4; ++j) {
    x[j] = b2f(v[j]);
    s += x[j];
    sq += x[j] * x[j];
  }
  for (int o = 32; o; o >>= 1) {
    s += __shfl_down(s, o);
    sq += __shfl_down(sq, o);
  }
  if (lane == 0) {
    red[wave] = s;
    red[4 + wave] = sq;
  }
  __syncthreads();
  s = red[0] + red[1] + red[2] + red[3];
  sq = red[4] + red[5] + red[6] + red[7];
  const float mean = s * (1.f / 1024.f);
  const float var = sq * (1.f / 1024.f) - mean * mean;
  const float rs = rsqrtf(var + 1e-12f);
  f32x4 gv = *(const f32x4*)(g + tid * 4);
  f32x4 bv = *(const f32x4*)(bta + tid * 4);
  u16x4 o;
#pragma unroll
  for (int j = 0; j < 4; ++j) o[j] = f2b((x[j] - mean) * rs * gv[j] + bv[j]);
  *(u16x4*)(out + (size_t)row * Dc + tid * 4) = o;
}

__global__ __launch_bounds__(256) void pool_k(
    const u16* __restrict__ s1, const float* __restrict__ pq,
    const u16* __restrict__ h, float* __restrict__ out) {
  const int b = blockIdx.x, tid = threadIdx.x;
  __shared__ float pqs[1024];
  __shared__ float sc[128];
  __shared__ float ex[128];
  for (int i = tid; i < 1024; i += 256) pqs[i] = pq[i];
  __syncthreads();
  if (tid < 128) {
    const u16* row = s1 + ((size_t)(b * 128 + tid)) * Dc;
    float s = 0.f;
    for (int c = 0; c < 128; ++c) {
      u16x8 v = *(const u16x8*)(row + c * 8);
#pragma unroll
      for (int j = 0; j < 8; ++j) s += b2f(v[j]) * pqs[c * 8 + j];
    }
    sc[tid] = s;
  }
  __syncthreads();
  float m = -1e30f;
  for (int t = 0; t < 128; ++t) m = fmaxf(m, sc[t]);
  if (tid < 128) ex[tid] = __expf(sc[tid] - m);
  __syncthreads();
  float sum = 0.f;
  for (int t = 0; t < 128; ++t) sum += ex[t];
  const int d0 = tid * 4;
  float acc[4] = {0.f, 0.f, 0.f, 0.f};
  for (int n = 0; n < 128; ++n) {
    const float w = ex[n];
    u16x4 v = *(const u16x4*)(h + ((size_t)(b * 128 + n)) * Dc + d0);
#pragma unroll
    for (int j = 0; j < 4; ++j) acc[j] += w * b2f(v[j]);
  }
  const float inv = 1.f / sum;
  f32x4 o;
#pragma unroll
  for (int j = 0; j < 4; ++j) o[j] = acc[j] * inv;
  *(f32x4*)(out + b * Dc + d0) = o;
}

// ---------------------------------------------------------------------------
extern "C" void kernel_launch(void* const* d_in, const int* in_sizes, int n_in,
                              void* d_out, int out_size, void* d_ws, size_t ws_size,
                              hipStream_t stream) {
  const float* x = (const float*)d_in[0];
  const float* wq_w = (const float*)d_in[1];
  const float* wq_b = (const float*)d_in[2];
  const float* wk_w = (const float*)d_in[3];
  const float* wk_b = (const float*)d_in[4];
  const float* hwq = (const float*)d_in[5];
  const float* hwk = (const float*)d_in[6];
  const float* tr_w = (const float*)d_in[7];
  const float* tr_b = (const float*)d_in[8];
  const float* so_w = (const float*)d_in[9];
  const float* so_b = (const float*)d_in[10];
  const float* ln1g = (const float*)d_in[11];
  const float* ln1b = (const float*)d_in[12];
  const float* int_w = (const float*)d_in[13];
  const float* int_b = (const float*)d_in[14];
  const float* out_w = (const float*)d_in[15];
  const float* out_b = (const float*)d_in[16];
  const float* ln2g = (const float*)d_in[17];
  const float* ln2b = (const float*)d_in[18];
  const float* pool_w = (const float*)d_in[19];
  const float* pool_b = (const float*)d_in[20];
  const float* pool_q = (const float*)d_in[21];

  char* w = (char*)d_ws;
  auto alloc = [&](size_t bytes) {
    char* p = w;
    w += (bytes + 255) & ~(size_t)255;
    return p;
  };
  u16* wTqk = (u16*)alloc((size_t)2 * Dc * Dc * 2);
  u16* wTtr = (u16*)alloc((size_t)Dc * Dc * 2);
  u16* wTso = (u16*)alloc((size_t)Dc * Dc * 2);
  u16* wTint = (u16*)alloc((size_t)Dc * Ic * 2);
  u16* wTout = (u16*)alloc((size_t)Dc * Ic * 2);
  u16* wTpool = (u16*)alloc((size_t)Dc * Dc * 2);
  u16* qb = (u16*)alloc((size_t)Mrows * Dc * 2);
  u16* kb = (u16*)alloc((size_t)Mrows * Dc * 2);
  u16* ab = (u16*)alloc((size_t)Mrows * Dc * 2);
  u16* tb = (u16*)alloc((size_t)Mrows * Dc * 2);
  u16* xc = (u16*)alloc((size_t)Mrows * Dc * 2);
  u16* hb = (u16*)alloc((size_t)Mrows * Ic * 2);
  if ((size_t)(w - (char*)d_ws) > ws_size) return;

  static constexpr size_t LDSB = 131072;
  static constexpr size_t LDSB2 = 98304;
  hipFuncSetAttribute((const void*)gemm256<0, true>, hipFuncAttributeMaxDynamicSharedMemorySize, LDSB);
  hipFuncSetAttribute((const void*)gemm256<2, false>, hipFuncAttributeMaxDynamicSharedMemorySize, LDSB);
  hipFuncSetAttribute((const void*)gemm128n<0>, hipFuncAttributeMaxDynamicSharedMemorySize, LDSB2);
  hipFuncSetAttribute((const void*)gemm128n<1>, hipFuncAttributeMaxDynamicSharedMemorySize, LDSB2);
  hipFuncSetAttribute((const void*)gemm128n<3>, hipFuncAttributeMaxDynamicSharedMemorySize, LDSB2);

  const dim3 blk(256);
  const dim3 blkG(512);
  const dim3 gT1(Dc / 32, Dc / 32);
  const dim3 gT4(Dc / 32, Dc / 32, 4);
  const dim3 gTio(Ic / 32, Dc / 32, 2);
  const dim3 gQK(2048 / 256, Mrows / 256);  // (8,32) = 256 blocks
  const dim3 gNi(Ic / 256, Mrows / 256);    // (16,32) = 512 blocks
  const dim3 gO(Dc / 128, Mrows / 256);     // (8,32) = 256 blocks

  cvt_k<<<(Mrows * Dc) / (256 * 8), blk, 0, stream>>>(x, xc);

  for (int i = 0; i < Lc; ++i) {
    transpose4sq<<<gT4, blk, 0, stream>>>(
        wq_w + (size_t)i * Dc * Dc, wk_w + (size_t)i * Dc * Dc,
        tr_w + (size_t)i * Dc * Dc, so_w + (size_t)i * Dc * Dc,
        wTqk, wTqk + (size_t)Dc * Dc, wTtr, wTso);
    transpose_io<<<gTio, blk, 0, stream>>>(
        int_w + (size_t)i * Dc * Ic, wTint, out_w + (size_t)i * Ic * Dc, wTout);

    // q | k = x @ [Wq ; Wk] (fused N=2048, split outputs)
    gemm256<0, true><<<gQK, blkG, LDSB, stream>>>(xc, wTqk, wq_b + i * Dc, wk_b + i * Dc,
                                                  nullptr, qb, kb, Mrows, 2048, Dc, Dc);
    // gq -> gk -> u = q*gk, one dispatch; u written into kb (head-local cols)
    attn_fused<<<Bc * Hc, 128, 0, stream>>>(qb, kb, hwq + i * Hc * HDc,
                                            hwk + i * Hc * HDc, kb);
    // attn_out = u@tr + tr_b + q
    gemm128n<1><<<gO, blkG, LDSB2, stream>>>(kb, wTtr, tr_b + i * Dc, qb, tb, Mrows, Dc, Dc, Dc);
    // t2 = attn_out@so + so_b ; a = LN1(t2)
    gemm128n<0><<<gO, blkG, LDSB2, stream>>>(tb, wTso, so_b + i * Dc, nullptr, kb, Mrows, Dc, Dc, Dc);
    ln_k<<<Mrows, blk, 0, stream>>>(kb, ln1g + i * Dc, ln1b + i * Dc, ab);
    // h = gelu(a@int + int_b)
    gemm256<2, false><<<gNi, blkG, LDSB, stream>>>(ab, wTint, int_b + i * Ic, nullptr,
                                                   nullptr, hb, nullptr, Mrows, Ic, Dc, Ic);
    // o+a = h@out + out_b + a ; x = LN2
    gemm128n<1><<<gO, blkG, LDSB2, stream>>>(hb, wTout, out_b + i * Dc, ab, tb, Mrows, Dc, Ic, Dc);
    ln_k<<<Mrows, blk, 0, stream>>>(tb, ln2g + i * Dc, ln2b + i * Dc, xc);
  }

  transpose_cvt<<<gT1, blk, 0, stream>>>(pool_w, wTpool, Dc, Dc);
  gemm128n<3><<<gO, blkG, LDSB2, stream>>>(xc, wTpool, pool_b, nullptr, tb, Mrows, Dc, Dc, Dc);
  pool_k<<<Bc, blk, 0, stream>>>(tb, pool_q, xc, (float*)d_out);
}